// Round 12
// baseline (870.082 us; speedup 1.0000x reference)
//
#include <hip/hip_runtime.h>

typedef _Float16 f16x8 __attribute__((ext_vector_type(8)));
typedef _Float16 f16x4 __attribute__((ext_vector_type(4)));
typedef float f32x4 __attribute__((ext_vector_type(4)));
typedef unsigned int u32;

#define MFMA16H(a, b, c) __builtin_amdgcn_mfma_f32_16x16x32_f16(a, b, c, 0, 0, 0)

#if __has_builtin(__builtin_amdgcn_exp2f)
#define EXP2F(x) __builtin_amdgcn_exp2f(x)
#else
#define EXP2F(x) exp2f(x)
#endif

#define LOG2E 1.44269504088896340736f

__device__ __forceinline__ f16x8 ldh8(const _Float16* p) {
  return *reinterpret_cast<const f16x8*>(p);
}

// ---------------- fused prep ----------------
// [0,2048): mask -> permuted fp16 table (masked -> -60000)
// [2048,3056): rel_bias -> permuted fp16 table rperm[h][d][lane][16]
// [3056,19440): fp32 -> fp16 conversions (q,k,v,wq,wk,wv,dw)
__global__ __launch_bounds__(256) void prep_kernel(
    const float* __restrict__ q, const float* __restrict__ k, const float* __restrict__ v,
    const float* __restrict__ wq, const float* __restrict__ wk, const float* __restrict__ wv,
    const float* __restrict__ dwt, const float* __restrict__ mask, const float* __restrict__ rel,
    _Float16* __restrict__ qf, _Float16* __restrict__ kf, _Float16* __restrict__ vf,
    _Float16* __restrict__ wqf, _Float16* __restrict__ wkf, _Float16* __restrict__ wvf,
    _Float16* __restrict__ dwf, _Float16* __restrict__ mperm, _Float16* __restrict__ rperm) {
  const int lane = threadIdx.x;
  const int w = lane >> 6, lg = (lane >> 4) & 3, lr = lane & 15;
  if (blockIdx.x < 2048) {
    const int blk = blockIdx.x;               // (b*32+qt64)*32 + kt
    const int kt = blk & 31, bq = blk >> 5;
    const int b = bq >> 5, qt = bq & 31;
    const int q0 = qt * 64;
    const float cs = -1e9f * LOG2E;
    _Float16 vals[16];
#pragma unroll
    for (int c = 0; c < 4; ++c)
#pragma unroll
      for (int r = 0; r < 4; ++r) {
        const int qr = q0 + w * 16 + lg * 4 + r;
        const int kc = kt * 64 + c * 16 + lr;
        vals[c * 4 + r] =
            (_Float16)fmaxf(mask[((size_t)b * 2048 + qr) * 2048 + kc] * cs, -60000.0f);
      }
    uint4* out = reinterpret_cast<uint4*>(mperm) + ((size_t)blk * 256 + lane) * 2;
    out[0] = *reinterpret_cast<uint4*>(&vals[0]);
    out[1] = *reinterpret_cast<uint4*>(&vals[8]);
    return;
  }
  if (blockIdx.x < 3056) {
    const int blk = blockIdx.x - 2048;        // h*63 + d
    const int h = blk / 63, d = blk % 63;
    _Float16 vals[16];
#pragma unroll
    for (int c = 0; c < 4; ++c)
#pragma unroll
      for (int r = 0; r < 4; ++r) {
        const int idx = (d - 31) * 64 + (w * 16 + lg * 4 + r) - (c * 16 + lr) + 2047;
        vals[c * 4 + r] = (_Float16)(rel[idx * 16 + h] * LOG2E);
      }
    uint4* out = reinterpret_cast<uint4*>(rperm) + ((size_t)blk * 256 + lane) * 2;
    out[0] = *reinterpret_cast<uint4*>(&vals[0]);
    out[1] = *reinterpret_cast<uint4*>(&vals[8]);
    return;
  }
  const int i = (blockIdx.x - 3056) * 256 + threadIdx.x;  // float4-group id
  const int r = i >> 18;  // 16 regions of 262144 groups
  const int j = i & 262143;
  const float* src;
  _Float16* dst;
  int off = 0;
  if (r < 4)       { src = q;   dst = qf;  off = r * 262144; }
  else if (r < 8)  { src = k;   dst = kf;  off = (r - 4) * 262144; }
  else if (r < 12) { src = v;   dst = vf;  off = (r - 8) * 262144; }
  else if (r == 12){ src = wq;  dst = wqf; }
  else if (r == 13){ src = wk;  dst = wkf; }
  else if (r == 14){ src = wv;  dst = wvf; }
  else             { src = dwt; dst = dwf; }
  const int g = off + j;
  float4 x = reinterpret_cast<const float4*>(src)[g];
  f16x4 h4;
  h4[0] = (_Float16)x.x; h4[1] = (_Float16)x.y;
  h4[2] = (_Float16)x.z; h4[3] = (_Float16)x.w;
  reinterpret_cast<f16x4*>(dst)[g] = h4;
}

// ---------------- GEMM body ----------------
__device__ __forceinline__ void gemm_body(
    int t, int mode, const _Float16* __restrict__ A, const _Float16* __restrict__ B,
    const float* __restrict__ bias, _Float16* __restrict__ out_h, float* __restrict__ out_f,
    _Float16* As, _Float16* Bs) {
  const int tid = threadIdx.x;
  const int tm = t & 31, tn = t >> 5;
  const int m0 = tm * 128, n0 = tn * 128;
  const int w = tid >> 6, l = tid & 63, lg = l >> 4, lr = l & 15;
  const int wr = w >> 1, wc = w & 1;
  const int srow = tid >> 2, scol = (tid & 3) * 8;

  f32x4 acc[4][4] = {};

  for (int kt = 0; kt < 32; ++kt) {
    const int k0 = kt * 32;
    uint4 ra[2], rb[2];
#pragma unroll
    for (int it = 0; it < 2; ++it) {
      const int row = it * 64 + srow;
      ra[it] = *reinterpret_cast<const uint4*>(A + (size_t)(m0 + row) * 1024 + k0 + scol);
      rb[it] = *reinterpret_cast<const uint4*>(B + (size_t)(n0 + row) * 1024 + k0 + scol);
    }
    __syncthreads();
#pragma unroll
    for (int it = 0; it < 2; ++it) {
      const int eo = (it * 256 + tid) * 8;
      *reinterpret_cast<uint4*>(As + eo) = ra[it];
      *reinterpret_cast<uint4*>(Bs + eo) = rb[it];
    }
    __syncthreads();

    f16x8 fa[4], fb[4];
#pragma unroll
    for (int i = 0; i < 4; ++i) {
      fa[i] = ldh8(As + (wr * 64 + i * 16 + lr) * 32 + lg * 8);
      fb[i] = ldh8(Bs + (wc * 64 + i * 16 + lr) * 32 + lg * 8);
    }
#pragma unroll
    for (int i = 0; i < 4; ++i)
#pragma unroll
      for (int j = 0; j < 4; ++j)
        acc[i][j] = MFMA16H(fa[i], fb[j], acc[i][j]);
  }

#pragma unroll
  for (int i = 0; i < 4; ++i) {
    const int mrow = m0 + wr * 64 + i * 16 + lg * 4;
#pragma unroll
    for (int j = 0; j < 4; ++j) {
      const int ncol = n0 + wc * 64 + j * 16 + lr;
      const float bv = bias[ncol];
#pragma unroll
      for (int r = 0; r < 4; ++r) {
        const int m = mrow + r;
        const float v = acc[i][j][r] + bv;
        if (mode == 2) {
          out_f[(size_t)m * 1024 + ncol] = v;
        } else {
          const int bb = m >> 11, s = m & 2047, hh = ncol >> 6, d = ncol & 63;
          if (mode == 0)
            out_h[((size_t)(bb * 16 + hh) * 2048 + s) * 64 + d] = (_Float16)v;
          else
            out_h[((size_t)(bb * 16 + hh) * 64 + d) * 2048 + s] = (_Float16)v;
        }
      }
    }
  }
}

// ---------------- fused projection GEMM (Q,K,V) ----------------
__global__ __launch_bounds__(256, 3) void proj_gemm_kernel(
    const _Float16* __restrict__ qf, const _Float16* __restrict__ kf, const _Float16* __restrict__ vf,
    const _Float16* __restrict__ wqf, const _Float16* __restrict__ wkf, const _Float16* __restrict__ wvf,
    const float* __restrict__ bq, const float* __restrict__ bk, const float* __restrict__ bv,
    _Float16* __restrict__ qhf, _Float16* __restrict__ khf, _Float16* __restrict__ vhT) {
  __shared__ __align__(16) _Float16 As[128 * 32];
  __shared__ __align__(16) _Float16 Bs[128 * 32];
  const int mode = blockIdx.x >> 8;
  const int t = blockIdx.x & 255;
  if (mode == 0)      gemm_body(t, 0, qf, wqf, bq, qhf, nullptr, As, Bs);
  else if (mode == 1) gemm_body(t, 0, kf, wkf, bk, khf, nullptr, As, Bs);
  else                gemm_body(t, 1, vf, wvf, bv, vhT, nullptr, As, Bs);
}

// ---------------- dense GEMM: A = o0 + o1 (fp16 partial contexts) ----------------
__global__ __launch_bounds__(256) void dense_gemm_kernel(
    const _Float16* __restrict__ A0, const _Float16* __restrict__ A1,
    const _Float16* __restrict__ Bw, const float* __restrict__ bias,
    float* __restrict__ out_f) {
  __shared__ __align__(16) _Float16 As[128 * 32];
  __shared__ __align__(16) _Float16 Bs[128 * 32];
  const int tid = threadIdx.x;
  const int t = blockIdx.x;
  const int tm = t & 31, tn = t >> 5;
  const int m0 = tm * 128, n0 = tn * 128;
  const int w = tid >> 6, l = tid & 63, lg = l >> 4, lr = l & 15;
  const int wr = w >> 1, wc = w & 1;
  const int srow = tid >> 2, scol = (tid & 3) * 8;

  f32x4 acc[4][4] = {};

  for (int kt = 0; kt < 32; ++kt) {
    const int k0 = kt * 32;
    f16x8 ra[2], rb[2];
#pragma unroll
    for (int it = 0; it < 2; ++it) {
      const int row = it * 64 + srow;
      const size_t ga = (size_t)(m0 + row) * 1024 + k0 + scol;
      ra[it] = ldh8(A0 + ga) + ldh8(A1 + ga);
      rb[it] = ldh8(Bw + (size_t)(n0 + row) * 1024 + k0 + scol);
    }
    __syncthreads();
#pragma unroll
    for (int it = 0; it < 2; ++it) {
      const int eo = (it * 256 + tid) * 8;
      *reinterpret_cast<f16x8*>(As + eo) = ra[it];
      *reinterpret_cast<f16x8*>(Bs + eo) = rb[it];
    }
    __syncthreads();

    f16x8 fa[4], fb[4];
#pragma unroll
    for (int i = 0; i < 4; ++i) {
      fa[i] = ldh8(As + (wr * 64 + i * 16 + lr) * 32 + lg * 8);
      fb[i] = ldh8(Bs + (wc * 64 + i * 16 + lr) * 32 + lg * 8);
    }
#pragma unroll
    for (int i = 0; i < 4; ++i)
#pragma unroll
      for (int j = 0; j < 4; ++j)
        acc[i][j] = MFMA16H(fa[i], fb[j], acc[i][j]);
  }

#pragma unroll
  for (int i = 0; i < 4; ++i) {
    const int mrow = m0 + wr * 64 + i * 16 + lg * 4;
#pragma unroll
    for (int j = 0; j < 4; ++j) {
      const int ncol = n0 + wc * 64 + j * 16 + lr;
      const float bv = bias[ncol];
#pragma unroll
      for (int r = 0; r < 4; ++r)
        out_f[(size_t)(mrow + r) * 1024 + ncol] = acc[i][j][r] + bv;
    }
  }
}

// ---------------- attention pass 1: row sums, k-split x2, zero LDS ----------------
__global__ __launch_bounds__(128, 8) void attn_sums_kernel(
    const _Float16* __restrict__ qh, const _Float16* __restrict__ kh,
    const _Float16* __restrict__ mperm, const _Float16* __restrict__ rperm,
    float* __restrict__ sums2) {
  const int bid = blockIdx.x;
  const int wg = ((bid & 7) << 9) | (bid >> 3);   // XCD-chunked (4096 = 8*512)
  const int half = wg & 1;
  const int qt = (wg >> 1) & 63;
  const int bh = wg >> 7;
  const int b = bh >> 4, h = bh & 15;
  const int q0 = qt * 32;
  const int tid = threadIdx.x;
  const int w2 = tid >> 6, l = tid & 63, lg = l >> 4, lr = l & 15;

  const size_t bh_off = (size_t)bh * 2048 * 64;
  const _Float16* qhb = qh + bh_off;
  const _Float16* khb = kh + bh_off;
  const int qt64 = qt >> 1;
  const int wp = (qt & 1) * 2 + w2;
  const int lanep = wp * 64 + lg * 16 + lr;
  const _Float16* mpb = mperm + ((size_t)(b * 32 + qt64) * 32 * 256 + lanep) * 16;
  const _Float16* rpb = rperm + ((size_t)(h * 63 + qt64 + 31) * 256 + lanep) * 16;

  f16x8 qfr[2];
  {
    const size_t qrow = (size_t)(q0 + w2 * 16 + lr) * 64;
    qfr[0] = ldh8(qhb + qrow + lg * 8);
    qfr[1] = ldh8(qhb + qrow + 32 + lg * 8);
  }

  const int qbase = w2 * 16 + lg * 4;
  const float c1 = 0.125f * LOG2E;
  float sacc[4] = {0.f, 0.f, 0.f, 0.f};

  const int kt0 = half * 16;
#pragma unroll 2
  for (int kt = kt0; kt < kt0 + 16; ++kt) {
    f16x8 b0 = ldh8(mpb + (size_t)kt * 4096) + ldh8(rpb - (size_t)kt * 4096);
    f16x8 b1 = ldh8(mpb + (size_t)kt * 4096 + 8) + ldh8(rpb - (size_t)kt * 4096 + 8);
#pragma unroll
    for (int c = 0; c < 4; ++c) {
      const int kc = kt * 64 + c * 16 + lr;
      const _Float16* kr = khb + (size_t)kc * 64 + lg * 8;
      f32x4 acc = {};
      acc = MFMA16H(qfr[0], ldh8(kr), acc);
      acc = MFMA16H(qfr[1], ldh8(kr + 32), acc);
#pragma unroll
      for (int r = 0; r < 4; ++r) {
        const float bias = (float)((c < 2) ? b0[(c & 1) * 4 + r] : b1[(c & 1) * 4 + r]);
        sacc[r] += EXP2F(fmaf(acc[r], c1, bias));
      }
    }
  }

#pragma unroll
  for (int r = 0; r < 4; ++r) {
    float s = sacc[r];
    s += __shfl_xor(s, 1);
    s += __shfl_xor(s, 2);
    s += __shfl_xor(s, 4);
    s += __shfl_xor(s, 8);
    if (lr == 0)
      sums2[((size_t)bh * 2048 + q0 + qbase + r) * 2 + half] = s;
  }
}

// ---------------- attention pass 2: k-split x2, normalized attn write + partial PV ----------------
__global__ __launch_bounds__(256, 8) void attn_emit_kernel(
    const _Float16* __restrict__ qh, const _Float16* __restrict__ kh,
    const _Float16* __restrict__ vT,
    const _Float16* __restrict__ mperm, const _Float16* __restrict__ rperm,
    const float* __restrict__ sums2, float* __restrict__ attn_out,
    _Float16* __restrict__ o0, _Float16* __restrict__ o1) {
  __shared__ __align__(16) _Float16 p16t[2][64 * 76];

  const int bid = blockIdx.x;
  const int wg = ((bid & 7) << 8) | (bid >> 3);   // XCD-chunked (2048 = 8*256)
  const int khalf = wg & 1;
  const int qt64 = (wg >> 1) & 31;
  const int bh = wg >> 6;
  const int b = bh >> 4, h = bh & 15;
  const int q0 = qt64 * 64;
  const int tid = threadIdx.x;
  const int w = tid >> 6, l = tid & 63, lg = l >> 4, lr = l & 15;

  const size_t bh_off = (size_t)bh * 2048 * 64;
  const _Float16* qhb = qh + bh_off;
  const _Float16* khb = kh + bh_off;
  const _Float16* vTb = vT + bh_off;
  const _Float16* mpb = mperm + ((size_t)(b * 32 + qt64) * 32 * 256 + tid) * 16;
  const _Float16* rpb = rperm + ((size_t)(h * 63 + qt64 + 31) * 256 + tid) * 16;
  float* attn_bh = attn_out + (size_t)bh * 2048 * 2048;
  _Float16* opart = khalf ? o1 : o0;

  const int qbase = w * 16 + lg * 4;

  f16x8 qfr[2];
  {
    const size_t qrow = (size_t)(q0 + w * 16 + lr) * 64;
    qfr[0] = ldh8(qhb + qrow + lg * 8);
    qfr[1] = ldh8(qhb + qrow + 32 + lg * 8);
  }
  float inv[4];
  {
    const float* sp = sums2 + ((size_t)bh * 2048 + q0 + qbase) * 2;
    float4 s0 = *reinterpret_cast<const float4*>(sp);
    float4 s1 = *reinterpret_cast<const float4*>(sp + 4);
    inv[0] = 1.0f / (s0.x + s0.y);
    inv[1] = 1.0f / (s0.z + s0.w);
    inv[2] = 1.0f / (s1.x + s1.y);
    inv[3] = 1.0f / (s1.z + s1.w);
  }

  const float c1 = 0.125f * LOG2E;
  f32x4 acc_o[4] = {};
  // store geometry (R10-proven): 16-lane group writes 256B contiguous per row
  const int sg = l >> 4, sc = (l & 15) * 4;

  const int kt0 = khalf * 16;
#pragma unroll 2
  for (int kt = kt0; kt < kt0 + 16; ++kt) {
    _Float16* tile = p16t[kt & 1];
    f16x8 b0 = ldh8(mpb + (size_t)kt * 4096) + ldh8(rpb - (size_t)kt * 4096);
    f16x8 b1 = ldh8(mpb + (size_t)kt * 4096 + 8) + ldh8(rpb - (size_t)kt * 4096 + 8);
#pragma unroll
    for (int c = 0; c < 4; ++c) {
      const int kc = kt * 64 + c * 16 + lr;
      const _Float16* kr = khb + (size_t)kc * 64 + lg * 8;
      f32x4 acc = {};
      acc = MFMA16H(qfr[0], ldh8(kr), acc);
      acc = MFMA16H(qfr[1], ldh8(kr + 32), acc);
#pragma unroll
      for (int r = 0; r < 4; ++r) {
        const float bias = (float)((c < 2) ? b0[(c & 1) * 4 + r] : b1[(c & 1) * 4 + r]);
        tile[(qbase + r) * 76 + c * 16 + lr] =
            (_Float16)(EXP2F(fmaf(acc[r], c1, bias)) * inv[r]);
      }
    }
    // PV from wave-local rows (same-wave DS ordering, no barrier)
    f16x8 pf0 = ldh8(tile + (w * 16 + lr) * 76 + lg * 8);
    f16x8 pf1 = ldh8(tile + (w * 16 + lr) * 76 + 32 + lg * 8);
#pragma unroll
    for (int n = 0; n < 4; ++n) {
      const _Float16* vr = vTb + (size_t)(n * 16 + lr) * 2048 + kt * 64 + lg * 8;
      acc_o[n] = MFMA16H(pf0, ldh8(vr), acc_o[n]);
      acc_o[n] = MFMA16H(pf1, ldh8(vr + 32), acc_o[n]);
    }
    // normalized attn write: rows w*16 + i*4 + sg, 256B contiguous per 16-lane group
#pragma unroll
    for (int i = 0; i < 4; ++i) {
      const int row = w * 16 + i * 4 + sg;
      f16x4 pw = *reinterpret_cast<const f16x4*>(tile + row * 76 + sc);
      float4 o;
      o.x = (float)pw[0]; o.y = (float)pw[1];
      o.z = (float)pw[2]; o.w = (float)pw[3];
      *reinterpret_cast<float4*>(attn_bh + (size_t)(q0 + row) * 2048 + kt * 64 + sc) = o;
    }
  }

#pragma unroll
  for (int n = 0; n < 4; ++n)
#pragma unroll
    for (int r = 0; r < 4; ++r) {
      const int qr = q0 + qbase + r;
      const int d = n * 16 + lr;
      opart[((size_t)(b * 2048 + qr) * 16 + h) * 64 + d] = (_Float16)acc_o[n][r];
    }
}

// ---------------- host ----------------
extern "C" void kernel_launch(void* const* d_in, const int* in_sizes, int n_in,
                              void* d_out, int out_size, void* d_ws, size_t ws_size,
                              hipStream_t stream) {
  const float* q = (const float*)d_in[0];
  const float* k = (const float*)d_in[1];
  const float* v = (const float*)d_in[2];
  const float* mask = (const float*)d_in[3];
  const float* wq_w = (const float*)d_in[4];
  const float* wq_b = (const float*)d_in[5];
  const float* wk_w = (const float*)d_in[6];
  const float* wk_b = (const float*)d_in[7];
  const float* wv_w = (const float*)d_in[8];
  const float* wv_b = (const float*)d_in[9];
  const float* dw = (const float*)d_in[10];
  const float* db = (const float*)d_in[11];
  const float* rel = (const float*)d_in[12];

  char* ws = (char*)d_ws;
  _Float16* qf_in = (_Float16*)(ws + 0);
  _Float16* kf_in = (_Float16*)(ws + 8388608);
  _Float16* vf_in = (_Float16*)(ws + 16777216);
  _Float16* wqf   = (_Float16*)(ws + 25165824);
  _Float16* wkf   = (_Float16*)(ws + 27262976);
  _Float16* wvf   = (_Float16*)(ws + 29360128);
  _Float16* dwf   = (_Float16*)(ws + 31457280);
  _Float16* qhf   = (_Float16*)(ws + 33554432);
  _Float16* khf   = (_Float16*)(ws + 41943040);
  _Float16* vhT   = (_Float16*)(ws + 50331648);
  _Float16* o0    = (_Float16*)(ws + 58720256);
  _Float16* o1    = (_Float16*)(ws + 67108864);
  float* sums2    = (float*)(ws + 75497472);            // 512 KB
  _Float16* mperm = (_Float16*)(ws + 76021760);         // 16.7 MB
  _Float16* rperm = (_Float16*)(ws + 92798976);         // 8.3 MB

  float* out = (float*)d_out;
  float* attn_out = out + 4194304;

  prep_kernel<<<19440, 256, 0, stream>>>(q, k, v, wq_w, wk_w, wv_w, dw, mask, rel,
                                         qf_in, kf_in, vf_in, wqf, wkf, wvf, dwf,
                                         mperm, rperm);

  proj_gemm_kernel<<<768, 256, 0, stream>>>(qf_in, kf_in, vf_in, wqf, wkf, wvf,
                                            wq_b, wk_b, wv_b, qhf, khf, vhT);

  attn_sums_kernel<<<4096, 128, 0, stream>>>(qhf, khf, mperm, rperm, sums2);

  attn_emit_kernel<<<2048, 256, 0, stream>>>(qhf, khf, vhT, mperm, rperm,
                                             sums2, attn_out, o0, o1);

  dense_gemm_kernel<<<256, 256, 0, stream>>>(o0, o1, dwf, db, out);
}

// Round 13
// 658.297 us; speedup vs baseline: 1.3217x; 1.3217x over previous
//
#include <hip/hip_runtime.h>

typedef _Float16 f16x8 __attribute__((ext_vector_type(8)));
typedef _Float16 f16x4 __attribute__((ext_vector_type(4)));
typedef float f32x4 __attribute__((ext_vector_type(4)));
typedef unsigned int u32;

#define MFMA16H(a, b, c) __builtin_amdgcn_mfma_f32_16x16x32_f16(a, b, c, 0, 0, 0)

#if __has_builtin(__builtin_amdgcn_exp2f)
#define EXP2F(x) __builtin_amdgcn_exp2f(x)
#else
#define EXP2F(x) exp2f(x)
#endif

#define LOG2E 1.44269504088896340736f

__device__ __forceinline__ f16x8 ldh8(const _Float16* p) {
  return *reinterpret_cast<const f16x8*>(p);
}

// ---------------- fused prep ----------------
// [0,2048): mask -> permuted fp16 table (masked -> -60000)
// [2048,3056): rel_bias -> permuted fp16 table rperm[h][d][lane][16]
// [3056,19440): fp32 -> fp16 conversions (q,k,v,wq,wk,wv,dw)
__global__ __launch_bounds__(256) void prep_kernel(
    const float* __restrict__ q, const float* __restrict__ k, const float* __restrict__ v,
    const float* __restrict__ wq, const float* __restrict__ wk, const float* __restrict__ wv,
    const float* __restrict__ dwt, const float* __restrict__ mask, const float* __restrict__ rel,
    _Float16* __restrict__ qf, _Float16* __restrict__ kf, _Float16* __restrict__ vf,
    _Float16* __restrict__ wqf, _Float16* __restrict__ wkf, _Float16* __restrict__ wvf,
    _Float16* __restrict__ dwf, _Float16* __restrict__ mperm, _Float16* __restrict__ rperm) {
  const int lane = threadIdx.x;
  const int w = lane >> 6, lg = (lane >> 4) & 3, lr = lane & 15;
  if (blockIdx.x < 2048) {
    const int blk = blockIdx.x;               // (b*32+qt64)*32 + kt
    const int kt = blk & 31, bq = blk >> 5;
    const int b = bq >> 5, qt = bq & 31;
    const int q0 = qt * 64;
    const float cs = -1e9f * LOG2E;
    _Float16 vals[16];
#pragma unroll
    for (int c = 0; c < 4; ++c)
#pragma unroll
      for (int r = 0; r < 4; ++r) {
        const int qr = q0 + w * 16 + lg * 4 + r;
        const int kc = kt * 64 + c * 16 + lr;
        vals[c * 4 + r] =
            (_Float16)fmaxf(mask[((size_t)b * 2048 + qr) * 2048 + kc] * cs, -60000.0f);
      }
    uint4* out = reinterpret_cast<uint4*>(mperm) + ((size_t)blk * 256 + lane) * 2;
    out[0] = *reinterpret_cast<uint4*>(&vals[0]);
    out[1] = *reinterpret_cast<uint4*>(&vals[8]);
    return;
  }
  if (blockIdx.x < 3056) {
    const int blk = blockIdx.x - 2048;        // h*63 + d
    const int h = blk / 63, d = blk % 63;
    _Float16 vals[16];
#pragma unroll
    for (int c = 0; c < 4; ++c)
#pragma unroll
      for (int r = 0; r < 4; ++r) {
        const int idx = (d - 31) * 64 + (w * 16 + lg * 4 + r) - (c * 16 + lr) + 2047;
        vals[c * 4 + r] = (_Float16)(rel[idx * 16 + h] * LOG2E);
      }
    uint4* out = reinterpret_cast<uint4*>(rperm) + ((size_t)blk * 256 + lane) * 2;
    out[0] = *reinterpret_cast<uint4*>(&vals[0]);
    out[1] = *reinterpret_cast<uint4*>(&vals[8]);
    return;
  }
  const int i = (blockIdx.x - 3056) * 256 + threadIdx.x;  // float4-group id
  const int r = i >> 18;  // 16 regions of 262144 groups
  const int j = i & 262143;
  const float* src;
  _Float16* dst;
  int off = 0;
  if (r < 4)       { src = q;   dst = qf;  off = r * 262144; }
  else if (r < 8)  { src = k;   dst = kf;  off = (r - 4) * 262144; }
  else if (r < 12) { src = v;   dst = vf;  off = (r - 8) * 262144; }
  else if (r == 12){ src = wq;  dst = wqf; }
  else if (r == 13){ src = wk;  dst = wkf; }
  else if (r == 14){ src = wv;  dst = wvf; }
  else             { src = dwt; dst = dwf; }
  const int g = off + j;
  float4 x = reinterpret_cast<const float4*>(src)[g];
  f16x4 h4;
  h4[0] = (_Float16)x.x; h4[1] = (_Float16)x.y;
  h4[2] = (_Float16)x.z; h4[3] = (_Float16)x.w;
  reinterpret_cast<f16x4*>(dst)[g] = h4;
}

// ---------------- GEMM body ----------------
__device__ __forceinline__ void gemm_body(
    int t, int mode, const _Float16* __restrict__ A, const _Float16* __restrict__ B,
    const float* __restrict__ bias, _Float16* __restrict__ out_h, float* __restrict__ out_f,
    _Float16* As, _Float16* Bs) {
  const int tid = threadIdx.x;
  const int tm = t & 31, tn = t >> 5;
  const int m0 = tm * 128, n0 = tn * 128;
  const int w = tid >> 6, l = tid & 63, lg = l >> 4, lr = l & 15;
  const int wr = w >> 1, wc = w & 1;
  const int srow = tid >> 2, scol = (tid & 3) * 8;

  f32x4 acc[4][4] = {};

  for (int kt = 0; kt < 32; ++kt) {
    const int k0 = kt * 32;
    uint4 ra[2], rb[2];
#pragma unroll
    for (int it = 0; it < 2; ++it) {
      const int row = it * 64 + srow;
      ra[it] = *reinterpret_cast<const uint4*>(A + (size_t)(m0 + row) * 1024 + k0 + scol);
      rb[it] = *reinterpret_cast<const uint4*>(B + (size_t)(n0 + row) * 1024 + k0 + scol);
    }
    __syncthreads();
#pragma unroll
    for (int it = 0; it < 2; ++it) {
      const int eo = (it * 256 + tid) * 8;
      *reinterpret_cast<uint4*>(As + eo) = ra[it];
      *reinterpret_cast<uint4*>(Bs + eo) = rb[it];
    }
    __syncthreads();

    f16x8 fa[4], fb[4];
#pragma unroll
    for (int i = 0; i < 4; ++i) {
      fa[i] = ldh8(As + (wr * 64 + i * 16 + lr) * 32 + lg * 8);
      fb[i] = ldh8(Bs + (wc * 64 + i * 16 + lr) * 32 + lg * 8);
    }
#pragma unroll
    for (int i = 0; i < 4; ++i)
#pragma unroll
      for (int j = 0; j < 4; ++j)
        acc[i][j] = MFMA16H(fa[i], fb[j], acc[i][j]);
  }

#pragma unroll
  for (int i = 0; i < 4; ++i) {
    const int mrow = m0 + wr * 64 + i * 16 + lg * 4;
#pragma unroll
    for (int j = 0; j < 4; ++j) {
      const int ncol = n0 + wc * 64 + j * 16 + lr;
      const float bv = bias[ncol];
#pragma unroll
      for (int r = 0; r < 4; ++r) {
        const int m = mrow + r;
        const float v = acc[i][j][r] + bv;
        if (mode == 2) {
          out_f[(size_t)m * 1024 + ncol] = v;
        } else {
          const int bb = m >> 11, s = m & 2047, hh = ncol >> 6, d = ncol & 63;
          if (mode == 0)
            out_h[((size_t)(bb * 16 + hh) * 2048 + s) * 64 + d] = (_Float16)v;
          else
            out_h[((size_t)(bb * 16 + hh) * 64 + d) * 2048 + s] = (_Float16)v;
        }
      }
    }
  }
}

// ---------------- fused projection GEMM (Q,K,V) ----------------
__global__ __launch_bounds__(256, 3) void proj_gemm_kernel(
    const _Float16* __restrict__ qf, const _Float16* __restrict__ kf, const _Float16* __restrict__ vf,
    const _Float16* __restrict__ wqf, const _Float16* __restrict__ wkf, const _Float16* __restrict__ wvf,
    const float* __restrict__ bq, const float* __restrict__ bk, const float* __restrict__ bv,
    _Float16* __restrict__ qhf, _Float16* __restrict__ khf, _Float16* __restrict__ vhT) {
  __shared__ __align__(16) _Float16 As[128 * 32];
  __shared__ __align__(16) _Float16 Bs[128 * 32];
  const int mode = blockIdx.x >> 8;
  const int t = blockIdx.x & 255;
  if (mode == 0)      gemm_body(t, 0, qf, wqf, bq, qhf, nullptr, As, Bs);
  else if (mode == 1) gemm_body(t, 0, kf, wkf, bk, khf, nullptr, As, Bs);
  else                gemm_body(t, 1, vf, wvf, bv, vhT, nullptr, As, Bs);
}

// ---------------- dense GEMM: A = o0 + o1 (fp16 partial contexts) ----------------
__global__ __launch_bounds__(256) void dense_gemm_kernel(
    const _Float16* __restrict__ A0, const _Float16* __restrict__ A1,
    const _Float16* __restrict__ Bw, const float* __restrict__ bias,
    float* __restrict__ out_f) {
  __shared__ __align__(16) _Float16 As[128 * 32];
  __shared__ __align__(16) _Float16 Bs[128 * 32];
  const int tid = threadIdx.x;
  const int t = blockIdx.x;
  const int tm = t & 31, tn = t >> 5;
  const int m0 = tm * 128, n0 = tn * 128;
  const int w = tid >> 6, l = tid & 63, lg = l >> 4, lr = l & 15;
  const int wr = w >> 1, wc = w & 1;
  const int srow = tid >> 2, scol = (tid & 3) * 8;

  f32x4 acc[4][4] = {};

  for (int kt = 0; kt < 32; ++kt) {
    const int k0 = kt * 32;
    f16x8 ra[2], rb[2];
#pragma unroll
    for (int it = 0; it < 2; ++it) {
      const int row = it * 64 + srow;
      const size_t ga = (size_t)(m0 + row) * 1024 + k0 + scol;
      ra[it] = ldh8(A0 + ga) + ldh8(A1 + ga);
      rb[it] = ldh8(Bw + (size_t)(n0 + row) * 1024 + k0 + scol);
    }
    __syncthreads();
#pragma unroll
    for (int it = 0; it < 2; ++it) {
      const int eo = (it * 256 + tid) * 8;
      *reinterpret_cast<f16x8*>(As + eo) = ra[it];
      *reinterpret_cast<f16x8*>(Bs + eo) = rb[it];
    }
    __syncthreads();

    f16x8 fa[4], fb[4];
#pragma unroll
    for (int i = 0; i < 4; ++i) {
      fa[i] = ldh8(As + (wr * 64 + i * 16 + lr) * 32 + lg * 8);
      fb[i] = ldh8(Bs + (wc * 64 + i * 16 + lr) * 32 + lg * 8);
    }
#pragma unroll
    for (int i = 0; i < 4; ++i)
#pragma unroll
      for (int j = 0; j < 4; ++j)
        acc[i][j] = MFMA16H(fa[i], fb[j], acc[i][j]);
  }

#pragma unroll
  for (int i = 0; i < 4; ++i) {
    const int mrow = m0 + wr * 64 + i * 16 + lg * 4;
#pragma unroll
    for (int j = 0; j < 4; ++j) {
      const int ncol = n0 + wc * 64 + j * 16 + lr;
      const float bv = bias[ncol];
#pragma unroll
      for (int r = 0; r < 4; ++r)
        out_f[(size_t)(mrow + r) * 1024 + ncol] = acc[i][j][r] + bv;
    }
  }
}

// ---------------- attention pass 1: row sums, k-split x2, zero LDS ----------------
__global__ __launch_bounds__(128, 4) void attn_sums_kernel(
    const _Float16* __restrict__ qh, const _Float16* __restrict__ kh,
    const _Float16* __restrict__ mperm, const _Float16* __restrict__ rperm,
    float* __restrict__ sums2) {
  const int bid = blockIdx.x;
  const int wg = ((bid & 7) << 9) | (bid >> 3);   // XCD-chunked (4096 = 8*512)
  const int half = wg & 1;
  const int qt = (wg >> 1) & 63;
  const int bh = wg >> 7;
  const int b = bh >> 4, h = bh & 15;
  const int q0 = qt * 32;
  const int tid = threadIdx.x;
  const int w2 = tid >> 6, l = tid & 63, lg = l >> 4, lr = l & 15;

  const size_t bh_off = (size_t)bh * 2048 * 64;
  const _Float16* qhb = qh + bh_off;
  const _Float16* khb = kh + bh_off;
  const int qt64 = qt >> 1;
  const int wp = (qt & 1) * 2 + w2;
  const int lanep = wp * 64 + lg * 16 + lr;
  const _Float16* mpb = mperm + ((size_t)(b * 32 + qt64) * 32 * 256 + lanep) * 16;
  const _Float16* rpb = rperm + ((size_t)(h * 63 + qt64 + 31) * 256 + lanep) * 16;

  f16x8 qfr[2];
  {
    const size_t qrow = (size_t)(q0 + w2 * 16 + lr) * 64;
    qfr[0] = ldh8(qhb + qrow + lg * 8);
    qfr[1] = ldh8(qhb + qrow + 32 + lg * 8);
  }

  const int qbase = w2 * 16 + lg * 4;
  const float c1 = 0.125f * LOG2E;
  float sacc[4] = {0.f, 0.f, 0.f, 0.f};

  const int kt0 = half * 16;
#pragma unroll 2
  for (int kt = kt0; kt < kt0 + 16; ++kt) {
    f16x8 b0 = ldh8(mpb + (size_t)kt * 4096) + ldh8(rpb - (size_t)kt * 4096);
    f16x8 b1 = ldh8(mpb + (size_t)kt * 4096 + 8) + ldh8(rpb - (size_t)kt * 4096 + 8);
#pragma unroll
    for (int c = 0; c < 4; ++c) {
      const int kc = kt * 64 + c * 16 + lr;
      const _Float16* kr = khb + (size_t)kc * 64 + lg * 8;
      f32x4 acc = {};
      acc = MFMA16H(qfr[0], ldh8(kr), acc);
      acc = MFMA16H(qfr[1], ldh8(kr + 32), acc);
#pragma unroll
      for (int r = 0; r < 4; ++r) {
        const float bias = (float)((c < 2) ? b0[(c & 1) * 4 + r] : b1[(c & 1) * 4 + r]);
        sacc[r] += EXP2F(fmaf(acc[r], c1, bias));
      }
    }
  }

#pragma unroll
  for (int r = 0; r < 4; ++r) {
    float s = sacc[r];
    s += __shfl_xor(s, 1);
    s += __shfl_xor(s, 2);
    s += __shfl_xor(s, 4);
    s += __shfl_xor(s, 8);
    if (lr == 0)
      sums2[((size_t)bh * 2048 + q0 + qbase + r) * 2 + half] = s;
  }
}

// ---------------- attention pass 2: k-split x2, normalized attn write + partial PV ----------------
__global__ __launch_bounds__(256, 4) void attn_emit_kernel(
    const _Float16* __restrict__ qh, const _Float16* __restrict__ kh,
    const _Float16* __restrict__ vT,
    const _Float16* __restrict__ mperm, const _Float16* __restrict__ rperm,
    const float* __restrict__ sums2, float* __restrict__ attn_out,
    _Float16* __restrict__ o0, _Float16* __restrict__ o1) {
  __shared__ __align__(16) _Float16 p16t[2][64 * 76];

  const int bid = blockIdx.x;
  const int wg = ((bid & 7) << 8) | (bid >> 3);   // XCD-chunked (2048 = 8*256)
  const int khalf = wg & 1;
  const int qt64 = (wg >> 1) & 31;
  const int bh = wg >> 6;
  const int b = bh >> 4, h = bh & 15;
  const int q0 = qt64 * 64;
  const int tid = threadIdx.x;
  const int w = tid >> 6, l = tid & 63, lg = l >> 4, lr = l & 15;

  const size_t bh_off = (size_t)bh * 2048 * 64;
  const _Float16* qhb = qh + bh_off;
  const _Float16* khb = kh + bh_off;
  const _Float16* vTb = vT + bh_off;
  const _Float16* mpb = mperm + ((size_t)(b * 32 + qt64) * 32 * 256 + tid) * 16;
  const _Float16* rpb = rperm + ((size_t)(h * 63 + qt64 + 31) * 256 + tid) * 16;
  float* attn_bh = attn_out + (size_t)bh * 2048 * 2048;
  _Float16* opart = khalf ? o1 : o0;

  const int qbase = w * 16 + lg * 4;

  f16x8 qfr[2];
  {
    const size_t qrow = (size_t)(q0 + w * 16 + lr) * 64;
    qfr[0] = ldh8(qhb + qrow + lg * 8);
    qfr[1] = ldh8(qhb + qrow + 32 + lg * 8);
  }
  float inv[4];
  {
    const float* sp = sums2 + ((size_t)bh * 2048 + q0 + qbase) * 2;
    float4 s0 = *reinterpret_cast<const float4*>(sp);
    float4 s1 = *reinterpret_cast<const float4*>(sp + 4);
    inv[0] = 1.0f / (s0.x + s0.y);
    inv[1] = 1.0f / (s0.z + s0.w);
    inv[2] = 1.0f / (s1.x + s1.y);
    inv[3] = 1.0f / (s1.z + s1.w);
  }

  const float c1 = 0.125f * LOG2E;
  f32x4 acc_o[4] = {};
  // store geometry: 16-lane group writes one row's 256B contiguous segment
  const int sg = l >> 4, sc = (l & 15) * 4;

  const int kt0 = khalf * 16;
#pragma unroll 2
  for (int kt = kt0; kt < kt0 + 16; ++kt) {
    _Float16* tile = p16t[kt & 1];
    f16x8 b0 = ldh8(mpb + (size_t)kt * 4096) + ldh8(rpb - (size_t)kt * 4096);
    f16x8 b1 = ldh8(mpb + (size_t)kt * 4096 + 8) + ldh8(rpb - (size_t)kt * 4096 + 8);
#pragma unroll
    for (int c = 0; c < 4; ++c) {
      const int kc = kt * 64 + c * 16 + lr;
      const _Float16* kr = khb + (size_t)kc * 64 + lg * 8;
      f32x4 acc = {};
      acc = MFMA16H(qfr[0], ldh8(kr), acc);
      acc = MFMA16H(qfr[1], ldh8(kr + 32), acc);
#pragma unroll
      for (int r = 0; r < 4; ++r) {
        const float bias = (float)((c < 2) ? b0[(c & 1) * 4 + r] : b1[(c & 1) * 4 + r]);
        tile[(qbase + r) * 76 + c * 16 + lr] =
            (_Float16)(EXP2F(fmaf(acc[r], c1, bias)) * inv[r]);
      }
    }
    // PV from wave-local rows (same-wave DS ordering, no barrier)
    f16x8 pf0 = ldh8(tile + (w * 16 + lr) * 76 + lg * 8);
    f16x8 pf1 = ldh8(tile + (w * 16 + lr) * 76 + 32 + lg * 8);
#pragma unroll
    for (int n = 0; n < 4; ++n) {
      const _Float16* vr = vTb + (size_t)(n * 16 + lr) * 2048 + kt * 64 + lg * 8;
      acc_o[n] = MFMA16H(pf0, ldh8(vr), acc_o[n]);
      acc_o[n] = MFMA16H(pf1, ldh8(vr + 32), acc_o[n]);
    }
    // normalized attn write: rows w*16 + i*4 + sg, one 16B ext-vector store/lane
#pragma unroll
    for (int i = 0; i < 4; ++i) {
      const int row = w * 16 + i * 4 + sg;
      f16x4 pw = *reinterpret_cast<const f16x4*>(tile + row * 76 + sc);
      f32x4 o;
      o[0] = (float)pw[0]; o[1] = (float)pw[1];
      o[2] = (float)pw[2]; o[3] = (float)pw[3];
      *reinterpret_cast<f32x4*>(attn_bh + (size_t)(q0 + row) * 2048 + kt * 64 + sc) = o;
    }
  }

#pragma unroll
  for (int n = 0; n < 4; ++n)
#pragma unroll
    for (int r = 0; r < 4; ++r) {
      const int qr = q0 + qbase + r;
      const int d = n * 16 + lr;
      opart[((size_t)(b * 2048 + qr) * 16 + h) * 64 + d] = (_Float16)acc_o[n][r];
    }
}

// ---------------- host ----------------
extern "C" void kernel_launch(void* const* d_in, const int* in_sizes, int n_in,
                              void* d_out, int out_size, void* d_ws, size_t ws_size,
                              hipStream_t stream) {
  const float* q = (const float*)d_in[0];
  const float* k = (const float*)d_in[1];
  const float* v = (const float*)d_in[2];
  const float* mask = (const float*)d_in[3];
  const float* wq_w = (const float*)d_in[4];
  const float* wq_b = (const float*)d_in[5];
  const float* wk_w = (const float*)d_in[6];
  const float* wk_b = (const float*)d_in[7];
  const float* wv_w = (const float*)d_in[8];
  const float* wv_b = (const float*)d_in[9];
  const float* dw = (const float*)d_in[10];
  const float* db = (const float*)d_in[11];
  const float* rel = (const float*)d_in[12];

  char* ws = (char*)d_ws;
  _Float16* qf_in = (_Float16*)(ws + 0);
  _Float16* kf_in = (_Float16*)(ws + 8388608);
  _Float16* vf_in = (_Float16*)(ws + 16777216);
  _Float16* wqf   = (_Float16*)(ws + 25165824);
  _Float16* wkf   = (_Float16*)(ws + 27262976);
  _Float16* wvf   = (_Float16*)(ws + 29360128);
  _Float16* dwf   = (_Float16*)(ws + 31457280);
  _Float16* qhf   = (_Float16*)(ws + 33554432);
  _Float16* khf   = (_Float16*)(ws + 41943040);
  _Float16* vhT   = (_Float16*)(ws + 50331648);
  _Float16* o0    = (_Float16*)(ws + 58720256);
  _Float16* o1    = (_Float16*)(ws + 67108864);
  float* sums2    = (float*)(ws + 75497472);            // 512 KB
  _Float16* mperm = (_Float16*)(ws + 76021760);         // 16.7 MB
  _Float16* rperm = (_Float16*)(ws + 92798976);         // 8.3 MB

  float* out = (float*)d_out;
  float* attn_out = out + 4194304;

  prep_kernel<<<19440, 256, 0, stream>>>(q, k, v, wq_w, wk_w, wv_w, dw, mask, rel,
                                         qf_in, kf_in, vf_in, wqf, wkf, wvf, dwf,
                                         mperm, rperm);

  proj_gemm_kernel<<<768, 256, 0, stream>>>(qf_in, kf_in, vf_in, wqf, wkf, wvf,
                                            wq_b, wk_b, wv_b, qhf, khf, vhT);

  attn_sums_kernel<<<4096, 128, 0, stream>>>(qhf, khf, mperm, rperm, sums2);

  attn_emit_kernel<<<2048, 256, 0, stream>>>(qhf, khf, vhT, mperm, rperm,
                                             sums2, attn_out, o0, o1);

  dense_gemm_kernel<<<256, 256, 0, stream>>>(o0, o1, dwf, db, out);
}